// Round 2
// baseline (161.408 us; speedup 1.0000x reference)
//
#include <hip/hip_runtime.h>

#define FEAT 256
#define EMB 256

typedef __attribute__((ext_vector_type(4))) float f32x4;
typedef __attribute__((ext_vector_type(8))) short short8;

// packed fp32x2 -> bf16x2 (RNE) in one instruction
__device__ __forceinline__ unsigned cvtpk(float lo, float hi) {
    unsigned r;
    asm volatile("v_cvt_pk_bf16_f32 %0, %1, %2" : "=v"(r) : "v"(lo), "v"(hi));
    return r;
}

// one-time W fp32 -> bf16 (65536 elements, 4/thread)
__global__ __launch_bounds__(256) void wprep(const float* __restrict__ W,
                                             ushort* __restrict__ Wb) {
    const int i = (blockIdx.x * 256 + threadIdx.x) * 4;
    f32x4 v = *(const f32x4*)(W + i);
    uint2 u = {cvtpk(v.x, v.y), cvtpk(v.z, v.w)};
    *(uint2*)(Wb + i) = u;
}

// h = X @ W^T quantized to int8 (biased-u8). H layout: row-major 256B rows,
// within-row byte order [blk(4)][cc(16)][j(4)] so dword (blk*16+cc) holds the
// 4 j-values (cols blk*64 + j*16 + cc) of MFMA lane cc -> single dword store.
// S[row][blk] = per-(row, 64-col block) dequant scale (wave-local absmax).
// B staged as plain uint2 copies from pre-converted bf16 W (half the bytes,
// no cvt) -- round-0 verified LDS layout, no async path.
__global__ __launch_bounds__(512) void gemm_q8(
    const float* __restrict__ X, const ushort* __restrict__ Wb,
    unsigned* __restrict__ H32, float* __restrict__ S, int M) {
    __shared__ ushort As[128][32];
    __shared__ ushort Bs[256][32];

    const int t    = threadIdx.x;
    const int lane = t & 63;
    const int wave = t >> 6;
    const int wr   = (wave >> 2) * 64;   // 0 or 64
    const int wc   = (wave & 3) * 64;    // 0,64,128,192
    const int m0   = blockIdx.x * 128;

    f32x4 acc[4][4] = {};

    const int srow = t >> 3;          // 0..63
    const int sc4  = (t & 7) * 4;     // col 0,4,...,28

    for (int k0 = 0; k0 < FEAT; k0 += 32) {
        __syncthreads();
        #pragma unroll
        for (int j = 0; j < 2; ++j) {
            int row = srow + 64 * j;
            int gr  = m0 + row;
            f32x4 v = {0.f, 0.f, 0.f, 0.f};
            if (gr < M) v = *(const f32x4*)(X + (size_t)gr * FEAT + k0 + sc4);
            uint2 u = {cvtpk(v.x, v.y), cvtpk(v.z, v.w)};
            *(uint2*)&As[row][sc4] = u;
        }
        #pragma unroll
        for (int j = 0; j < 4; ++j) {
            int row = srow + 64 * j;
            uint2 uw = *(const uint2*)(Wb + (size_t)row * FEAT + k0 + sc4);
            *(uint2*)&Bs[row][sc4] = uw;
        }
        __syncthreads();

        const int r  = lane & 15;
        const int kr = (lane >> 4) * 8;
        short8 a[4], b[4];
        #pragma unroll
        for (int i = 0; i < 4; ++i) a[i] = *(const short8*)&As[wr + i * 16 + r][kr];
        #pragma unroll
        for (int j = 0; j < 4; ++j) b[j] = *(const short8*)&Bs[wc + j * 16 + r][kr];
        #pragma unroll
        for (int i = 0; i < 4; ++i)
            #pragma unroll
            for (int j = 0; j < 4; ++j)
                acc[i][j] = __builtin_amdgcn_mfma_f32_16x16x32_bf16(a[i], b[j], acc[i][j], 0, 0, 0);
    }

    // epilogue: C/D mapping col = wc + j*16 + (lane&15), row = wr + i*16 + (lane>>4)*4 + q.
    const int g  = lane >> 4;
    const int cc = lane & 15;
    const int b  = wave & 3;          // 64-col block index (= wc/64)
    #pragma unroll
    for (int i = 0; i < 4; ++i) {
        #pragma unroll
        for (int q = 0; q < 4; ++q) {
            const int row = m0 + wr + i * 16 + g * 4 + q;
            float mx = fmaxf(fmaxf(fabsf(acc[i][0][q]), fabsf(acc[i][1][q])),
                             fmaxf(fabsf(acc[i][2][q]), fabsf(acc[i][3][q])));
            mx = fmaxf(mx, __shfl_xor(mx, 1, 64));
            mx = fmaxf(mx, __shfl_xor(mx, 2, 64));
            mx = fmaxf(mx, __shfl_xor(mx, 4, 64));
            mx = fmaxf(mx, __shfl_xor(mx, 8, 64));
            const float inv = mx > 1e-30f ? 127.0f * __builtin_amdgcn_rcpf(mx) : 0.0f;
            if (row < M) {
                unsigned wdw = 0;
                #pragma unroll
                for (int j = 0; j < 4; ++j) {
                    int u = (int)fmaf(acc[i][j][q], inv, 128.5f);
                    u = u < 0 ? 0 : (u > 255 ? 255 : u);
                    wdw |= (unsigned)u << (8 * j);
                }
                H32[(size_t)row * 64 + b * 16 + cc] = wdw;
                if (cc == 0) S[(size_t)row * 4 + b] = mx * (1.0f / 127.0f);
            }
        }
    }
}

// edge_dst is sorted: rp[n] = first edge with dst >= n; rp[N] = E.
__global__ __launch_bounds__(256) void build_rowptr(
    const int* __restrict__ dst, int* __restrict__ rp, int E, int N) {
    int e = blockIdx.x * 256 + threadIdx.x;
    if (e >= E) return;
    int d    = dst[e];
    int prev = (e == 0) ? -1 : dst[e - 1];
    for (int n = prev + 1; n <= d; ++n) rp[n] = e;
    if (e == E - 1) {
        for (int n = d + 1; n <= N; ++n) rp[n] = E;
    }
}

// SpMM over int8 H. 16-lane group per node; lane owns 16 bytes of the 256B row.
// Bulk loop: 4 guaranteed-full edges (16 rows in flight/wave, zero duplicate
// gathers); scalar 1-edge tail. Dequant bias-correction:
// out = sum(vs*u) - 128*sum(vs). NT stores for write-once out.
__global__ __launch_bounds__(256) void spmm_q8(
    const uint4* __restrict__ H16, const float* __restrict__ S,
    const int* __restrict__ rp, const int* __restrict__ src,
    const float* __restrict__ val, float* __restrict__ out, int M) {
    const int lane = threadIdx.x & 63;
    const int wave = threadIdx.x >> 6;
    const int li   = lane & 15;          // lane within group
    const int grp  = lane >> 4;          // group 0..3
    const int b    = li >> 2;            // 64-col block
    const int node = blockIdx.x * 16 + wave * 4 + grp;
    if (node >= M) return;
    const int lo = rp[node], hi = rp[node + 1];

    float a0[16], a1[16];                // k = d*4 + j
    #pragma unroll
    for (int k = 0; k < 16; ++k) { a0[k] = 0.f; a1[k] = 0.f; }
    float corr = 0.f;

    int e = lo;
    for (; e + 3 < hi; e += 4) {
        const int s0 = src[e],     s1 = src[e + 1];
        const int s2 = src[e + 2], s3 = src[e + 3];
        const float v0 = val[e],     v1 = val[e + 1];
        const float v2 = val[e + 2], v3 = val[e + 3];
        const float vs0 = v0 * S[(size_t)s0 * 4 + b];
        const float vs1 = v1 * S[(size_t)s1 * 4 + b];
        const float vs2 = v2 * S[(size_t)s2 * 4 + b];
        const float vs3 = v3 * S[(size_t)s3 * 4 + b];
        const uint4 p0 = H16[(size_t)s0 * 16 + li];
        const uint4 p1 = H16[(size_t)s1 * 16 + li];
        const uint4 p2 = H16[(size_t)s2 * 16 + li];
        const uint4 p3 = H16[(size_t)s3 * 16 + li];
        corr += (vs0 + vs1) + (vs2 + vs3);
        const unsigned q0[4] = {p0.x, p0.y, p0.z, p0.w};
        const unsigned q1[4] = {p1.x, p1.y, p1.z, p1.w};
        const unsigned q2[4] = {p2.x, p2.y, p2.z, p2.w};
        const unsigned q3[4] = {p3.x, p3.y, p3.z, p3.w};
        #pragma unroll
        for (int d = 0; d < 4; ++d) {
            #pragma unroll
            for (int j = 0; j < 4; ++j) {
                a0[d * 4 + j] += vs0 * (float)((q0[d] >> (8 * j)) & 0xffu)
                               + vs2 * (float)((q2[d] >> (8 * j)) & 0xffu);
                a1[d * 4 + j] += vs1 * (float)((q1[d] >> (8 * j)) & 0xffu)
                               + vs3 * (float)((q3[d] >> (8 * j)) & 0xffu);
            }
        }
    }
    for (; e < hi; ++e) {               // 0..3 leftover edges, no duplicates
        const int s0 = src[e];
        const float vs0 = val[e] * S[(size_t)s0 * 4 + b];
        const uint4 p0 = H16[(size_t)s0 * 16 + li];
        corr += vs0;
        const unsigned q0[4] = {p0.x, p0.y, p0.z, p0.w};
        #pragma unroll
        for (int d = 0; d < 4; ++d) {
            #pragma unroll
            for (int j = 0; j < 4; ++j)
                a0[d * 4 + j] += vs0 * (float)((q0[d] >> (8 * j)) & 0xffu);
        }
    }

    const float corrs = corr * 128.0f;
    float* const obase = out + (size_t)node * EMB + b * 64 + (li & 3) * 4;
    #pragma unroll
    for (int j = 0; j < 4; ++j) {
        f32x4 o = {a0[j]      + a1[j]      - corrs,
                   a0[4 + j]  + a1[4 + j]  - corrs,
                   a0[8 + j]  + a1[8 + j]  - corrs,
                   a0[12 + j] + a1[12 + j] - corrs};
        __builtin_nontemporal_store(o, (f32x4*)(obase + j * 16));
    }
}

extern "C" void kernel_launch(void* const* d_in, const int* in_sizes, int n_in,
                              void* d_out, int out_size, void* d_ws, size_t ws_size,
                              hipStream_t stream) {
    const float* x    = (const float*)d_in[0];
    const float* w    = (const float*)d_in[1];
    const int*   esrc = (const int*)d_in[2];
    const int*   edst = (const int*)d_in[3];
    const float* eval = (const float*)d_in[4];

    const int M = in_sizes[0] / FEAT;   // 100000
    const int E = in_sizes[2];          // 1600000

    unsigned* Hbuf = (unsigned*)d_ws;                               // [M][64] dwords (int8 rows)
    float*    S    = (float*)((char*)d_ws + (size_t)M * 256);       // [M][4] scales
    int*      rp   = (int*)((char*)S + (size_t)M * 4 * sizeof(float));
    size_t    woff = (size_t)M * 256 + (size_t)M * 16 + (size_t)(M + 1) * 4;
    woff = (woff + 255) & ~(size_t)255;
    ushort*   Wb   = (ushort*)((char*)d_ws + woff);                 // [256][256] bf16

    wprep<<<(EMB * FEAT / 4 + 255) / 256, 256, 0, stream>>>(w, Wb);
    gemm_q8<<<(M + 127) / 128, 512, 0, stream>>>(x, Wb, Hbuf, S, M);
    build_rowptr<<<(E + 255) / 256, 256, 0, stream>>>(edst, rp, E, M);
    spmm_q8<<<(M + 15) / 16, 256, 0, stream>>>((const uint4*)Hbuf, S, rp, esrc, eval,
                                               (float*)d_out, M);
}

// Round 3
// 127.075 us; speedup vs baseline: 1.2702x; 1.2702x over previous
//
#include <hip/hip_runtime.h>

#define FEAT 256
#define EMB 256

typedef __attribute__((ext_vector_type(4))) float f32x4;
typedef __attribute__((ext_vector_type(8))) short short8;

// packed fp32x2 -> bf16x2 (RNE) in one instruction
__device__ __forceinline__ unsigned cvtpk(float lo, float hi) {
    unsigned r;
    asm volatile("v_cvt_pk_bf16_f32 %0, %1, %2" : "=v"(r) : "v"(lo), "v"(hi));
    return r;
}

// h = X @ W^T quantized to int8 (biased-u8). H layout: row-major 256B rows,
// within-row byte order [blk(4)][cc(16)][j(4)] so dword (blk*16+cc) holds the
// 4 j-values (cols blk*64 + j*16 + cc) of MFMA lane cc -> single dword store.
// S[row][blk] = per-(row, 64-col block) dequant scale (wave-local absmax).
// Register-prefetch pipeline: step k+1's X/W loads issue right after the
// post-stage barrier and retire at step k+1's LDS write -> global latency
// hides under ds_read + 16 MFMA + barrier (kernel was latency-bound: all
// pipes <18% busy in round-2 counters).
__global__ __launch_bounds__(512) void gemm_q8(
    const float* __restrict__ X, const float* __restrict__ W,
    unsigned* __restrict__ H32, float* __restrict__ S, int M) {
    __shared__ ushort As[128][32];
    __shared__ ushort Bs[256][32];

    const int t    = threadIdx.x;
    const int lane = t & 63;
    const int wave = t >> 6;
    const int wr   = (wave >> 2) * 64;   // 0 or 64
    const int wc   = (wave & 3) * 64;    // 0,64,128,192
    const int m0   = blockIdx.x * 128;

    f32x4 acc[4][4] = {};

    const int srow = t >> 3;          // 0..63
    const int sc4  = (t & 7) * 4;     // col 0,4,...,28
    const int gr0  = m0 + srow;
    const int gr1  = m0 + srow + 64;
    const float* const xp0 = X + (size_t)gr0 * FEAT + sc4;
    const float* const xp1 = X + (size_t)gr1 * FEAT + sc4;
    const float* const wp  = W + (size_t)srow * FEAT + sc4;

    // prologue: load step 0
    f32x4 xv0 = {0.f, 0.f, 0.f, 0.f}, xv1 = {0.f, 0.f, 0.f, 0.f};
    f32x4 wv[4];
    if (gr0 < M) xv0 = *(const f32x4*)xp0;
    if (gr1 < M) xv1 = *(const f32x4*)xp1;
    #pragma unroll
    for (int j = 0; j < 4; ++j) wv[j] = *(const f32x4*)(wp + (size_t)j * 64 * FEAT);

    for (int k0 = 0; k0 < FEAT; k0 += 32) {
        __syncthreads();   // prev step's ds_reads done; LDS reusable
        {
            uint2 u0 = {cvtpk(xv0.x, xv0.y), cvtpk(xv0.z, xv0.w)};
            uint2 u1 = {cvtpk(xv1.x, xv1.y), cvtpk(xv1.z, xv1.w)};
            *(uint2*)&As[srow][sc4]      = u0;
            *(uint2*)&As[srow + 64][sc4] = u1;
            #pragma unroll
            for (int j = 0; j < 4; ++j) {
                uint2 uw = {cvtpk(wv[j].x, wv[j].y), cvtpk(wv[j].z, wv[j].w)};
                *(uint2*)&Bs[srow + 64 * j][sc4] = uw;
            }
        }
        __syncthreads();

        // issue next step's loads now; they drain at the NEXT LDS write
        if (k0 + 32 < FEAT) {
            const int kn = k0 + 32;
            xv0 = {0.f, 0.f, 0.f, 0.f};
            xv1 = {0.f, 0.f, 0.f, 0.f};
            if (gr0 < M) xv0 = *(const f32x4*)(xp0 + kn);
            if (gr1 < M) xv1 = *(const f32x4*)(xp1 + kn);
            #pragma unroll
            for (int j = 0; j < 4; ++j)
                wv[j] = *(const f32x4*)(wp + (size_t)j * 64 * FEAT + kn);
        }

        const int r  = lane & 15;
        const int kr = (lane >> 4) * 8;
        short8 a[4], b[4];
        #pragma unroll
        for (int i = 0; i < 4; ++i) a[i] = *(const short8*)&As[wr + i * 16 + r][kr];
        #pragma unroll
        for (int j = 0; j < 4; ++j) b[j] = *(const short8*)&Bs[wc + j * 16 + r][kr];
        #pragma unroll
        for (int i = 0; i < 4; ++i)
            #pragma unroll
            for (int j = 0; j < 4; ++j)
                acc[i][j] = __builtin_amdgcn_mfma_f32_16x16x32_bf16(a[i], b[j], acc[i][j], 0, 0, 0);
    }

    // epilogue: C/D mapping col = wc + j*16 + (lane&15), row = wr + i*16 + (lane>>4)*4 + q.
    const int g  = lane >> 4;
    const int cc = lane & 15;
    const int b  = wave & 3;          // 64-col block index (= wc/64)
    #pragma unroll
    for (int i = 0; i < 4; ++i) {
        #pragma unroll
        for (int q = 0; q < 4; ++q) {
            const int row = m0 + wr + i * 16 + g * 4 + q;
            float mx = fmaxf(fmaxf(fabsf(acc[i][0][q]), fabsf(acc[i][1][q])),
                             fmaxf(fabsf(acc[i][2][q]), fabsf(acc[i][3][q])));
            mx = fmaxf(mx, __shfl_xor(mx, 1, 64));
            mx = fmaxf(mx, __shfl_xor(mx, 2, 64));
            mx = fmaxf(mx, __shfl_xor(mx, 4, 64));
            mx = fmaxf(mx, __shfl_xor(mx, 8, 64));
            const float inv = mx > 1e-30f ? 127.0f * __builtin_amdgcn_rcpf(mx) : 0.0f;
            if (row < M) {
                unsigned wdw = 0;
                #pragma unroll
                for (int j = 0; j < 4; ++j) {
                    int u = (int)fmaf(acc[i][j][q], inv, 128.5f);
                    u = u < 0 ? 0 : (u > 255 ? 255 : u);
                    wdw |= (unsigned)u << (8 * j);
                }
                H32[(size_t)row * 64 + b * 16 + cc] = wdw;
                if (cc == 0) S[(size_t)row * 4 + b] = mx * (1.0f / 127.0f);
            }
        }
    }
}

// edge_dst is sorted: rp[n] = first edge with dst >= n; rp[N] = E.
__global__ __launch_bounds__(256) void build_rowptr(
    const int* __restrict__ dst, int* __restrict__ rp, int E, int N) {
    int e = blockIdx.x * 256 + threadIdx.x;
    if (e >= E) return;
    int d    = dst[e];
    int prev = (e == 0) ? -1 : dst[e - 1];
    for (int n = prev + 1; n <= d; ++n) rp[n] = e;
    if (e == E - 1) {
        for (int n = d + 1; n <= N; ++n) rp[n] = E;
    }
}

// SpMM over int8 H (256B rows). 16-lane group per node (4 nodes/wave); lane
// owns 16 bytes (one uint4) of the row. Dual chains = 8 edges in flight/wave.
// Dequant bias-correction: out = sum(vs*u) - 128*sum(vs). NT stores.
// (Round-0 proven form; 4-deep variants measured neutral-to-worse.)
__global__ __launch_bounds__(256) void spmm_q8(
    const uint4* __restrict__ H16, const float* __restrict__ S,
    const int* __restrict__ rp, const int* __restrict__ src,
    const float* __restrict__ val, float* __restrict__ out, int M) {
    const int lane = threadIdx.x & 63;
    const int wave = threadIdx.x >> 6;
    const int li   = lane & 15;          // lane within group
    const int grp  = lane >> 4;          // group 0..3
    const int b    = li >> 2;            // 64-col block
    const int node = blockIdx.x * 16 + wave * 4 + grp;
    if (node >= M) return;
    const int lo = rp[node], hi = rp[node + 1];

    float a0[16], a1[16];                // k = d*4 + j
    #pragma unroll
    for (int k = 0; k < 16; ++k) { a0[k] = 0.f; a1[k] = 0.f; }
    float corr0 = 0.f, corr1 = 0.f;

    for (int e = lo; e < hi; e += 2) {
        const int e1 = e + 1;
        const int c1 = e1 < hi ? e1 : e;
        const int s0 = src[e], s1 = src[c1];
        const float v0 = val[e];
        float v1 = e1 < hi ? val[c1] : 0.f;
        const float vs0 = v0 * S[(size_t)s0 * 4 + b];
        const float vs1 = v1 * S[(size_t)s1 * 4 + b];
        const uint4 p0 = H16[(size_t)s0 * 16 + li];
        const uint4 p1 = H16[(size_t)s1 * 16 + li];
        corr0 += vs0;
        corr1 += vs1;
        const unsigned pd0[4] = {p0.x, p0.y, p0.z, p0.w};
        const unsigned pd1[4] = {p1.x, p1.y, p1.z, p1.w};
        #pragma unroll
        for (int d = 0; d < 4; ++d) {
            #pragma unroll
            for (int j = 0; j < 4; ++j) {
                a0[d * 4 + j] += vs0 * (float)((pd0[d] >> (8 * j)) & 0xffu);
                a1[d * 4 + j] += vs1 * (float)((pd1[d] >> (8 * j)) & 0xffu);
            }
        }
    }

    const float corr = (corr0 + corr1) * 128.0f;
    float* const obase = out + (size_t)node * EMB + b * 64 + (li & 3) * 4;
    #pragma unroll
    for (int j = 0; j < 4; ++j) {
        f32x4 o = {a0[j]      + a1[j]      - corr,
                   a0[4 + j]  + a1[4 + j]  - corr,
                   a0[8 + j]  + a1[8 + j]  - corr,
                   a0[12 + j] + a1[12 + j] - corr};
        __builtin_nontemporal_store(o, (f32x4*)(obase + j * 16));
    }
}

extern "C" void kernel_launch(void* const* d_in, const int* in_sizes, int n_in,
                              void* d_out, int out_size, void* d_ws, size_t ws_size,
                              hipStream_t stream) {
    const float* x    = (const float*)d_in[0];
    const float* w    = (const float*)d_in[1];
    const int*   esrc = (const int*)d_in[2];
    const int*   edst = (const int*)d_in[3];
    const float* eval = (const float*)d_in[4];

    const int M = in_sizes[0] / FEAT;   // 100000
    const int E = in_sizes[2];          // 1600000

    unsigned* Hbuf = (unsigned*)d_ws;                               // [M][64] dwords (int8 rows)
    float*    S    = (float*)((char*)d_ws + (size_t)M * 256);       // [M][4] scales
    int*      rp   = (int*)((char*)S + (size_t)M * 4 * sizeof(float));

    gemm_q8<<<(M + 127) / 128, 512, 0, stream>>>(x, w, Hbuf, S, M);
    build_rowptr<<<(E + 255) / 256, 256, 0, stream>>>(edst, rp, E, M);
    spmm_q8<<<(M + 15) / 16, 256, 0, stream>>>((const uint4*)Hbuf, S, rp, esrc, eval,
                                               (float*)d_out, M);
}